// Round 19
// baseline (239.544 us; speedup 1.0000x reference)
//
#include <hip/hip_runtime.h>
#include <hip/hip_bf16.h>

#define EPS 1e-8f
#define LEAK 0.2f

#define B 8
#define CIN 256
#define F 128
#define L 2048
#define LU 4096
#define Z 256
#define NZ 100
#define S (F * LU)

typedef __attribute__((ext_vector_type(8))) short bf16x8;
typedef __attribute__((ext_vector_type(4))) float f32x4;

__device__ inline unsigned short f2bf(float x) {
    unsigned u = __builtin_bit_cast(unsigned, x);
    u += 0x7fffu + ((u >> 16) & 1u);
    return (unsigned short)(u >> 16);
}
__device__ inline float bf2f(unsigned short h) {
    unsigned u = ((unsigned)h) << 16;
    return __builtin_bit_cast(float, u);
}
__device__ inline unsigned pack2(float a, float b) {
    __hip_bfloat162 h = __float22bfloat162_rn(make_float2(a, b));  // v_cvt_pk_bf16_f32
    unsigned u;
    __builtin_memcpy(&u, &h, 4);
    return u;
}
__device__ inline bf16x8 cvtfrag(float4 a, float4 b) {
    uint4 u;
    u.x = pack2(a.x, a.y); u.y = pack2(a.z, a.w);
    u.z = pack2(b.x, b.y); u.w = pack2(b.z, b.w);
    return __builtin_bit_cast(bf16x8, u);
}
__device__ inline void gload_lds16(const void* g, void* l) {
    __builtin_amdgcn_global_load_lds((const __attribute__((address_space(1))) void*)g,
                                     (__attribute__((address_space(3))) void*)l, 16, 0, 0);
}

// ---------------- styles + demod + prepw fused (passing) ----------------
__global__ void k_styles(const float* __restrict__ istyle,
                         const float* __restrict__ s1w, const float* __restrict__ s1b,
                         const float* __restrict__ s2w, const float* __restrict__ s2b,
                         const float* __restrict__ rgbw, const float* __restrict__ rgbb,
                         const float* __restrict__ rgbcw,
                         const float* __restrict__ W1, const float* __restrict__ W2,
                         float* __restrict__ s1, float* __restrict__ s2,
                         float* __restrict__ srgbS,
                         float* __restrict__ d1, float* __restrict__ d2,
                         unsigned short* __restrict__ Wt1, unsigned short* __restrict__ Wt2) {
    int t = threadIdx.x;
    {
        int i = blockIdx.x * 256 + t;
        if (i < 3 * F * CIN) {
            int kk = i / (F * CIN);
            int rem = i - kk * (F * CIN);
            int f = rem >> 8, c = rem & 255;
            Wt1[i] = f2bf(W1[(f * CIN + c) * 3 + kk]);
        }
        if (i < 3 * F * F) {
            int kk = i / (F * F);
            int rem = i - kk * (F * F);
            int f = rem >> 7, c = rem & 127;
            Wt2[i] = f2bf(W2[(f * F + c) * 3 + kk]);
        }
    }
    if (blockIdx.x >= 8) return;
    __shared__ float is[Z];
    __shared__ float sh1[CIN];
    __shared__ float sh2[F];
    int b = blockIdx.x;
    if (t < Z) is[t] = istyle[b * Z + t];
    __syncthreads();
    {
        float acc = 0.f;
        const float* w = s1w + (size_t)t * Z;
        for (int z = 0; z < Z; z += 4) {
            float4 v = *(const float4*)(w + z);
            acc += v.x * is[z] + v.y * is[z + 1] + v.z * is[z + 2] + v.w * is[z + 3];
        }
        float v = acc + s1b[t] + 1.0f;
        sh1[t] = v;
        s1[b * CIN + t] = v;
    }
    if (t < F) {
        float a2 = 0.f, a3 = 0.f;
        const float* w2 = s2w + (size_t)t * Z;
        const float* w3 = rgbw + (size_t)t * Z;
        for (int z = 0; z < Z; z += 4) {
            float4 u2 = *(const float4*)(w2 + z);
            float4 u3 = *(const float4*)(w3 + z);
            a2 += u2.x * is[z] + u2.y * is[z + 1] + u2.z * is[z + 2] + u2.w * is[z + 3];
            a3 += u3.x * is[z] + u3.y * is[z + 1] + u3.z * is[z + 2] + u3.w * is[z + 3];
        }
        float v2 = a2 + s2b[t] + 1.0f;
        sh2[t] = v2;
        s2[b * F + t] = v2;
        srgbS[b * F + t] = (a3 + rgbb[t] + 1.0f) * rgbcw[t];
    }
    __syncthreads();
    if (t < F) {
        float acc = 0.f;
        const float* w = W1 + (size_t)t * CIN * 3;
        for (int c = 0; c < CIN; c += 4) {
            float4 va = *(const float4*)(w + c * 3);
            float4 vb = *(const float4*)(w + c * 3 + 4);
            float4 vc = *(const float4*)(w + c * 3 + 8);
            float s0 = sh1[c], s1v = sh1[c + 1], s2v = sh1[c + 2], s3 = sh1[c + 3];
            acc += s0 * s0 * (va.x * va.x + va.y * va.y + va.z * va.z);
            acc += s1v * s1v * (va.w * va.w + vb.x * vb.x + vb.y * vb.y);
            acc += s2v * s2v * (vb.z * vb.z + vb.w * vb.w + vc.x * vc.x);
            acc += s3 * s3 * (vc.y * vc.y + vc.z * vc.z + vc.w * vc.w);
        }
        d1[b * F + t] = rsqrtf(acc + EPS);
    } else {
        int f = t - F;
        float acc = 0.f;
        const float* w = W2 + (size_t)f * F * 3;
        for (int c = 0; c < F; c += 4) {
            float4 va = *(const float4*)(w + c * 3);
            float4 vb = *(const float4*)(w + c * 3 + 4);
            float4 vc = *(const float4*)(w + c * 3 + 8);
            float s0 = sh2[c], s1v = sh2[c + 1], s2v = sh2[c + 2], s3 = sh2[c + 3];
            acc += s0 * s0 * (va.x * va.x + va.y * va.y + va.z * va.z);
            acc += s1v * s1v * (va.w * va.w + vb.x * vb.x + vb.y * vb.y);
            acc += s2v * s2v * (vb.z * vb.z + vb.w * vb.w + vc.x * vc.x);
            acc += s3 * s3 * (vc.y * vc.y + vc.z * vc.z + vc.w * vc.w);
        }
        d2[b * F + f] = rsqrtf(acc + EPS);
    }
}

// ---------------- prep: xt[b][l][c] = upsample(x)*s1, bf16 (parked in d_out) ----------
__global__ __launch_bounds__(256) void k_prepx(const float* __restrict__ x,
                                               const float* __restrict__ s1,
                                               unsigned short* __restrict__ xt) {
    int b = blockIdx.z, c0 = blockIdx.y * 64, l0 = blockIdx.x * 64;
    int t = threadIdx.x;
    __shared__ float xj[64][37];
    int j0 = (l0 >> 1) - 1;
    for (int idx = t; idx < 64 * 34; idx += 256) {
        int c = idx / 34, jj = idx - c * 34;
        int j = j0 + jj;
        j = j < 0 ? 0 : (j > L - 1 ? L - 1 : j);
        xj[c][jj] = x[((size_t)(b * CIN + c0 + c)) * L + j];
    }
    __syncthreads();
    int c = t & 63;
    int lg = t >> 6;
    float s = s1[b * CIN + c0 + c];
    for (int li = 0; li < 16; ++li) {
        int ll = lg * 16 + li;
        int l = l0 + ll;
        int j = l >> 1;
        int jj = j - j0;
        float v;
        if (l & 1) {
            v = 0.75f * xj[c][jj] + 0.25f * xj[c][jj + 1];
        } else {
            v = (j == 0) ? xj[c][jj] : (0.25f * xj[c][jj - 1] + 0.75f * xj[c][jj]);
        }
        xt[((size_t)(b * LU + l)) * CIN + c0 + c] = f2bf(v * s);
    }
}

// ---------------- conv1 MFMA (unchanged) ----------------
__global__ __launch_bounds__(256) void k_conv1(const unsigned short* __restrict__ xt,
                                               const unsigned short* __restrict__ Wt1,
                                               const float* __restrict__ d1,
                                               unsigned short* __restrict__ y1) {
    const int b0 = blockIdx.y * 2;
    const int l0 = blockIdx.x * 64;
    const int nfb = blockIdx.z * 4;
    const int lane = threadIdx.x & 63, wv = threadIdx.x >> 6;
    const int lbase = l0 + wv * 16;
    const int m = lane & 15, ks = lane >> 4;

    f32x4 acc[2][4];
#pragma unroll
    for (int bb = 0; bb < 2; ++bb)
#pragma unroll
        for (int nf = 0; nf < 4; ++nf) acc[bb][nf] = (f32x4)0.f;

    const unsigned short* xb0 = xt + ((size_t)(b0 + 0) * LU) * CIN + ks * 8;
    const unsigned short* xb1 = xt + ((size_t)(b0 + 1) * LU) * CIN + ks * 8;

#pragma unroll 2
    for (int kc = 0; kc < 8; ++kc) {
#pragma unroll
        for (int kk = 0; kk < 3; ++kk) {
            int lA = lbase + m + kk - 1;
            bf16x8 a0 = (bf16x8)0, a1 = (bf16x8)0;
            if (lA >= 0 && lA < LU) {
                a0 = *(const bf16x8*)&xb0[(size_t)lA * CIN + kc * 32];
                a1 = *(const bf16x8*)&xb1[(size_t)lA * CIN + kc * 32];
            }
#pragma unroll
            for (int nf = 0; nf < 4; ++nf) {
                const bf16x8 w =
                    *(const bf16x8*)&Wt1[((kk * F + (nfb + nf) * 16 + m) << 8) + kc * 32 + ks * 8];
                acc[0][nf] = __builtin_amdgcn_mfma_f32_16x16x32_bf16(a0, w, acc[0][nf], 0, 0, 0);
                acc[1][nf] = __builtin_amdgcn_mfma_f32_16x16x32_bf16(a1, w, acc[1][nf], 0, 0, 0);
            }
        }
    }
#pragma unroll
    for (int bb = 0; bb < 2; ++bb) {
        int b = b0 + bb;
#pragma unroll
        for (int nf = 0; nf < 4; ++nf) {
            int f = (nfb + nf) * 16 + m;
            float dm = d1[b * F + f];
#pragma unroll
            for (int q = 0; q < 4; ++q) {
                int l = lbase + ks * 4 + q;
                y1[((size_t)(b * LU + l) << 7) + f] = f2bf(acc[bb][nf][q] * dm);
            }
        }
    }
}

// ---------------- noise1 v11: DMA staging + MFMA noise-GEMM ---------------------------
// Chunk = 64 rows; wave w computes rows w*16..w*16+15 via 4x mfma_16x16x32_bf16.
// A = inoise (batch x z, rows>=8 and z>=100 zeroed), built ONCE in VGPRs -> no in-loop
// scalar loads (the r10-r18 stall source). B from staged LDS + cvt_pk. ks<2 lanes RMW.
__global__ __launch_bounds__(256) void k_noise1(unsigned short* y1,
                                                const float* __restrict__ nw,
                                                const float* __restrict__ inoise,
                                                const float* __restrict__ s2) {
    __shared__ float lds[2][6400];  // 2 x 25.6 KB
    const int t = threadIdx.x;
    const int lane = t & 63, wv = t >> 6;
    const int n = lane & 15, ks = lane >> 4;   // row-in-tile / k-slice (& batch group)
    const bool w0 = (t >> 6) == 0;
    const int f0 = (blockIdx.x >> 8) * 32;
    const int l0 = (blockIdx.x & 255) * 16;
    const int r = wv * 16 + n;                 // row in chunk
    const int fseg = r >> 1, dl = r & 1;
    const int f = f0 + fseg;

    // ---- A fragments (once) ----
    bf16x8 af[4];
#pragma unroll
    for (int ck = 0; ck < 4; ++ck) {
        bf16x8 a = (bf16x8)0;
        if (n < 8) {
            const float* ap = inoise + n * NZ;
#pragma unroll
            for (int j = 0; j < 8; ++j) {
                int z = ck * 32 + ks * 8 + j;
                if (z < NZ) a[j] = (short)f2bf(ap[z]);
            }
        }
        af[ck] = a;
    }

    // ---- prologue hoist: y1 + s2 for this lane's (row, 4 batches) ----
    unsigned short yv[8][4] = {};
    float s2v[4] = {};
    if (ks < 2) {
#pragma unroll
        for (int q = 0; q < 4; ++q) s2v[q] = s2[(ks * 4 + q) * F + f];
#pragma unroll
        for (int cc = 0; cc < 8; ++cc) {
            int l = l0 + 2 * cc + dl;
            size_t i = (size_t)l * F + f;
#pragma unroll
            for (int q = 0; q < 4; ++q) yv[cc][q] = y1[(size_t)(ks * 4 + q) * S + i];
        }
    }

    auto stage = [&](int buf, int cc) {
        const int lbase = l0 + 2 * cc;
#pragma unroll
        for (int rr = 0; rr < 7; ++rr) {
            int g = rr * 256 + t;
            if (g < 1600) {
                int fs = g / 50;
                int rem = g - fs * 50;
                int d2 = (rem >= 25) ? 1 : 0;
                int m = rem - 25 * d2;
                const float* src = nw + ((size_t)(f0 + fs) * LU + lbase + d2) * NZ + m * 4;
                gload_lds16(src, &lds[buf][g * 4]);
            }
        }
    };

    auto compute = [&](int buf, int cc) {
        const float* rowp = &lds[buf][r * 100];
        f32x4 acc = (f32x4)0.f;
#pragma unroll
        for (int ck = 0; ck < 3; ++ck) {
            float4 u0 = *(const float4*)&rowp[ck * 32 + ks * 8];
            float4 u1 = *(const float4*)&rowp[ck * 32 + ks * 8 + 4];
            acc = __builtin_amdgcn_mfma_f32_16x16x32_bf16(af[ck], cvtfrag(u0, u1), acc, 0, 0, 0);
        }
        {
            bf16x8 b3 = (bf16x8)0;
            if (ks == 0) {
                float4 u = *(const float4*)&rowp[96];
                unsigned p0 = pack2(u.x, u.y), p1 = pack2(u.z, u.w);
                b3[0] = (short)(p0 & 0xffff); b3[1] = (short)(p0 >> 16);
                b3[2] = (short)(p1 & 0xffff); b3[3] = (short)(p1 >> 16);
            }
            acc = __builtin_amdgcn_mfma_f32_16x16x32_bf16(af[3], b3, acc, 0, 0, 0);
        }
        if (ks < 2) {
            const int l = l0 + 2 * cc + dl;
            const size_t i = (size_t)l * F + f;
#pragma unroll
            for (int q = 0; q < 4; ++q) {
                float val = bf2f(yv[cc][q]) + acc[q];
                val = val >= 0.f ? val : LEAK * val;
                y1[(size_t)(ks * 4 + q) * S + i] = f2bf(val * s2v[q]);
            }
        }
    };

    stage(0, 0);
    stage(1, 1);

#define WSTEP(N0, N1)                                                       \
    if (w0) { asm volatile("s_waitcnt vmcnt(" #N0 ")" ::: "memory"); }      \
    else    { asm volatile("s_waitcnt vmcnt(" #N1 ")" ::: "memory"); }      \
    __builtin_amdgcn_s_barrier();                                           \
    __builtin_amdgcn_sched_barrier(0);

    WSTEP(7, 6)              compute(0, 0);
    WSTEP(4, 4) stage(0, 2); compute(1, 1);
    WSTEP(4, 4) stage(1, 3); compute(0, 2);
    WSTEP(4, 4) stage(0, 4); compute(1, 3);
    WSTEP(4, 4) stage(1, 5); compute(0, 4);
    WSTEP(4, 4) stage(0, 6); compute(1, 5);
    WSTEP(4, 4) stage(1, 7); compute(0, 6);
    WSTEP(4, 4)              compute(1, 7);
#undef WSTEP
}

// ---------------- conv2 MFMA (unchanged) ----------------
__global__ __launch_bounds__(256) void k_conv2(const unsigned short* __restrict__ y1n,
                                               const unsigned short* __restrict__ Wt2,
                                               const float* __restrict__ d2,
                                               float* __restrict__ xout) {
    const int b0 = blockIdx.y * 2;
    const int l0 = blockIdx.x * 64;
    const int mfb = blockIdx.z * 4;
    const int lane = threadIdx.x & 63, wv = threadIdx.x >> 6;
    const int lbase = l0 + wv * 16;
    const int m = lane & 15, ks = lane >> 4;

    f32x4 acc[2][4];
#pragma unroll
    for (int bb = 0; bb < 2; ++bb)
#pragma unroll
        for (int mf = 0; mf < 4; ++mf) acc[bb][mf] = (f32x4)0.f;

    const unsigned short* yb0 = y1n + ((size_t)(b0 + 0) * LU) * F + ks * 8;
    const unsigned short* yb1 = y1n + ((size_t)(b0 + 1) * LU) * F + ks * 8;

#pragma unroll 2
    for (int kc = 0; kc < 4; ++kc) {
#pragma unroll
        for (int kk = 0; kk < 3; ++kk) {
            int lB = lbase + m + kk - 1;
            bf16x8 bv0 = (bf16x8)0, bv1 = (bf16x8)0;
            if (lB >= 0 && lB < LU) {
                bv0 = *(const bf16x8*)&yb0[(size_t)lB * F + kc * 32];
                bv1 = *(const bf16x8*)&yb1[(size_t)lB * F + kc * 32];
            }
#pragma unroll
            for (int mf = 0; mf < 4; ++mf) {
                const bf16x8 w =
                    *(const bf16x8*)&Wt2[((kk * F + (mfb + mf) * 16 + m) << 7) + kc * 32 + ks * 8];
                acc[0][mf] = __builtin_amdgcn_mfma_f32_16x16x32_bf16(w, bv0, acc[0][mf], 0, 0, 0);
                acc[1][mf] = __builtin_amdgcn_mfma_f32_16x16x32_bf16(w, bv1, acc[1][mf], 0, 0, 0);
            }
        }
    }
#pragma unroll
    for (int bb = 0; bb < 2; ++bb) {
        int b = b0 + bb;
#pragma unroll
        for (int mf = 0; mf < 4; ++mf) {
#pragma unroll
            for (int q = 0; q < 4; ++q) {
                int f = (mfb + mf) * 16 + ks * 4 + q;
                int l = lbase + m;
                xout[((size_t)(b * F + f) << 12) + l] = acc[bb][mf][q] * d2[b * F + f];
            }
        }
    }
}

// ---------------- noise2 v10: DMA staging + MFMA noise-GEMM (contiguous rows) ---------
__global__ __launch_bounds__(256) void k_noise2(const float* __restrict__ nw,
                                                const float* __restrict__ inoise,
                                                float* xio) {
    __shared__ float lds[2][6400];
    const int t = threadIdx.x;
    const int lane = t & 63, wv = t >> 6;
    const int n = lane & 15, ks = lane >> 4;
    const bool w0 = (t >> 6) == 0;
    const int row0 = blockIdx.x * 512;
    const int r = wv * 16 + n;

    bf16x8 af[4];
#pragma unroll
    for (int ck = 0; ck < 4; ++ck) {
        bf16x8 a = (bf16x8)0;
        if (n < 8) {
            const float* ap = inoise + n * NZ;
#pragma unroll
            for (int j = 0; j < 8; ++j) {
                int z = ck * 32 + ks * 8 + j;
                if (z < NZ) a[j] = (short)f2bf(ap[z]);
            }
        }
        af[ck] = a;
    }

    float xv[8][4] = {};
    if (ks < 2) {
#pragma unroll
        for (int cc = 0; cc < 8; ++cc) {
            size_t i = (size_t)row0 + cc * 64 + r;
#pragma unroll
            for (int q = 0; q < 4; ++q) xv[cc][q] = xio[(size_t)(ks * 4 + q) * S + i];
        }
    }

    auto stage = [&](int buf, int cc) {
        const float* src0 = nw + ((size_t)row0 + cc * 64) * NZ;
#pragma unroll
        for (int rr = 0; rr < 7; ++rr) {
            int g = rr * 256 + t;
            if (g < 1600) gload_lds16(src0 + g * 4, &lds[buf][g * 4]);
        }
    };

    auto compute = [&](int buf, int cc) {
        const float* rowp = &lds[buf][r * 100];
        f32x4 acc = (f32x4)0.f;
#pragma unroll
        for (int ck = 0; ck < 3; ++ck) {
            float4 u0 = *(const float4*)&rowp[ck * 32 + ks * 8];
            float4 u1 = *(const float4*)&rowp[ck * 32 + ks * 8 + 4];
            acc = __builtin_amdgcn_mfma_f32_16x16x32_bf16(af[ck], cvtfrag(u0, u1), acc, 0, 0, 0);
        }
        {
            bf16x8 b3 = (bf16x8)0;
            if (ks == 0) {
                float4 u = *(const float4*)&rowp[96];
                unsigned p0 = pack2(u.x, u.y), p1 = pack2(u.z, u.w);
                b3[0] = (short)(p0 & 0xffff); b3[1] = (short)(p0 >> 16);
                b3[2] = (short)(p1 & 0xffff); b3[3] = (short)(p1 >> 16);
            }
            acc = __builtin_amdgcn_mfma_f32_16x16x32_bf16(af[3], b3, acc, 0, 0, 0);
        }
        if (ks < 2) {
            const size_t i = (size_t)row0 + cc * 64 + r;
#pragma unroll
            for (int q = 0; q < 4; ++q) {
                float val = xv[cc][q] + acc[q];
                val = val >= 0.f ? val : LEAK * val;
                xio[(size_t)(ks * 4 + q) * S + i] = val;
            }
        }
    };

    stage(0, 0);
    stage(1, 1);

#define WSTEP(N0, N1)                                                       \
    if (w0) { asm volatile("s_waitcnt vmcnt(" #N0 ")" ::: "memory"); }      \
    else    { asm volatile("s_waitcnt vmcnt(" #N1 ")" ::: "memory"); }      \
    __builtin_amdgcn_s_barrier();                                           \
    __builtin_amdgcn_sched_barrier(0);

    WSTEP(7, 6)              compute(0, 0);
    WSTEP(4, 4) stage(0, 2); compute(1, 1);
    WSTEP(4, 4) stage(1, 3); compute(0, 2);
    WSTEP(4, 4) stage(0, 4); compute(1, 3);
    WSTEP(4, 4) stage(1, 5); compute(0, 4);
    WSTEP(4, 4) stage(0, 6); compute(1, 5);
    WSTEP(4, 4) stage(1, 7); compute(0, 6);
    WSTEP(4, 4)              compute(1, 7);
#undef WSTEP
}

// ---------------- rgb fused (unchanged) ----------------
__global__ __launch_bounds__(256) void k_rgb(const float* __restrict__ xf,
                                             const float* __restrict__ srgbS,
                                             const float* __restrict__ prev,
                                             float* __restrict__ rgb) {
    int b = blockIdx.y;
    int o0 = blockIdx.x * 512;
    int t = threadIdx.x;
    __shared__ float ss[F];
    __shared__ float pre[258];
    if (t < F) ss[t] = srgbS[b * F + t];
    __syncthreads();
    int j0 = (o0 >> 1) - 1;
    for (int jj = t; jj < 258; jj += 256) {
        int j = j0 + jj;
        j = j < 0 ? 0 : (j > LU - 1 ? LU - 1 : j);
        float acc = prev[b * LU + j];
        const float* xb = xf + (size_t)b * S + j;
        for (int f = 0; f < F; ++f) acc += xb[(size_t)f * LU] * ss[f];
        pre[jj] = acc;
    }
    __syncthreads();
    int jj = t + 1;
    int j = j0 + jj;
    float ve = (j == 0) ? pre[jj] : (0.25f * pre[jj - 1] + 0.75f * pre[jj]);
    float vo = 0.75f * pre[jj] + 0.25f * pre[jj + 1];
    float2 v2 = make_float2(ve, vo);
    *(float2*)&rgb[(size_t)b * 2 * LU + o0 + 2 * t] = v2;
}

extern "C" void kernel_launch(void* const* d_in, const int* in_sizes, int n_in,
                              void* d_out, int out_size, void* d_ws, size_t ws_size,
                              hipStream_t stream) {
    const float* x      = (const float*)d_in[0];
    const float* prev   = (const float*)d_in[1];
    const float* istyle = (const float*)d_in[2];
    const float* inoise = (const float*)d_in[3];
    const float* s1w    = (const float*)d_in[4];
    const float* s1b    = (const float*)d_in[5];
    const float* W1     = (const float*)d_in[6];
    const float* nw1    = (const float*)d_in[7];
    const float* s2w    = (const float*)d_in[8];
    const float* s2b    = (const float*)d_in[9];
    const float* W2     = (const float*)d_in[10];
    const float* nw2    = (const float*)d_in[11];
    const float* rgbw   = (const float*)d_in[12];
    const float* rgbb   = (const float*)d_in[13];
    const float* rgbcw  = (const float*)d_in[14];

    char* w = (char*)d_ws;
    float* s1      = (float*)(w);                             // 8 KB
    float* s2      = (float*)(w + 8 * 1024);                  // 4 KB
    float* srgbS   = (float*)(w + 12 * 1024);                 // 4 KB
    float* d1      = (float*)(w + 16 * 1024);                 // 4 KB
    float* d2      = (float*)(w + 20 * 1024);                 // 4 KB
    unsigned short* Wt1 = (unsigned short*)(w + 256 * 1024);  // 192 KB
    unsigned short* Wt2 = (unsigned short*)(w + 448 * 1024);  // 96 KB
    unsigned short* y1  = (unsigned short*)(w + (size_t)1024 * 1024);  // 8 MB

    unsigned short* xt = (unsigned short*)d_out;  // parked; dead once conv2 writes xout

    float* xout   = (float*)d_out;
    float* rgbout = xout + (size_t)B * S;

    k_styles<<<384, 256, 0, stream>>>(istyle, s1w, s1b, s2w, s2b, rgbw, rgbb, rgbcw,
                                      W1, W2, s1, s2, srgbS, d1, d2, Wt1, Wt2);
    k_prepx<<<dim3(LU / 64, CIN / 64, B), 256, 0, stream>>>(x, s1, xt);
    k_conv1<<<dim3(LU / 64, B / 2, 2), 256, 0, stream>>>(xt, Wt1, d1, y1);
    k_noise1<<<1024, 256, 0, stream>>>(y1, nw1, inoise, s2);
    k_conv2<<<dim3(LU / 64, B / 2, 2), 256, 0, stream>>>(y1, Wt2, d2, xout);
    k_noise2<<<1024, 256, 0, stream>>>(nw2, inoise, xout);
    k_rgb<<<dim3(2 * LU / 512, B), 256, 0, stream>>>(xout, srgbS, prev, rgbout);
}

// Round 20
// 224.881 us; speedup vs baseline: 1.0652x; 1.0652x over previous
//
#include <hip/hip_runtime.h>
#include <hip/hip_bf16.h>

#define EPS 1e-8f
#define LEAK 0.2f

#define B 8
#define CIN 256
#define F 128
#define L 2048
#define LU 4096
#define Z 256
#define NZ 100
#define S (F * LU)

typedef __attribute__((ext_vector_type(8))) short bf16x8;
typedef __attribute__((ext_vector_type(4))) float f32x4;

__device__ inline unsigned short f2bf(float x) {
    unsigned u = __builtin_bit_cast(unsigned, x);
    u += 0x7fffu + ((u >> 16) & 1u);
    return (unsigned short)(u >> 16);
}
__device__ inline float bf2f(unsigned short h) {
    unsigned u = ((unsigned)h) << 16;
    return __builtin_bit_cast(float, u);
}
__device__ inline unsigned pack2(float a, float b) {
    __hip_bfloat162 h = __float22bfloat162_rn(make_float2(a, b));
    unsigned u;
    __builtin_memcpy(&u, &h, 4);
    return u;
}
__device__ inline bf16x8 cvtfrag(float4 a, float4 b) {
    uint4 u;
    u.x = pack2(a.x, a.y); u.y = pack2(a.z, a.w);
    u.z = pack2(b.x, b.y); u.w = pack2(b.z, b.w);
    return __builtin_bit_cast(bf16x8, u);
}
__device__ inline void gload_lds16(const void* g, void* l) {
    __builtin_amdgcn_global_load_lds((const __attribute__((address_space(1))) void*)g,
                                     (__attribute__((address_space(3))) void*)l, 16, 0, 0);
}

// ---------------- styles + demod + prepw fused (passing) ----------------
__global__ void k_styles(const float* __restrict__ istyle,
                         const float* __restrict__ s1w, const float* __restrict__ s1b,
                         const float* __restrict__ s2w, const float* __restrict__ s2b,
                         const float* __restrict__ rgbw, const float* __restrict__ rgbb,
                         const float* __restrict__ rgbcw,
                         const float* __restrict__ W1, const float* __restrict__ W2,
                         float* __restrict__ s1, float* __restrict__ s2,
                         float* __restrict__ srgbS,
                         float* __restrict__ d1, float* __restrict__ d2,
                         unsigned short* __restrict__ Wt1, unsigned short* __restrict__ Wt2) {
    int t = threadIdx.x;
    {
        int i = blockIdx.x * 256 + t;
        if (i < 3 * F * CIN) {
            int kk = i / (F * CIN);
            int rem = i - kk * (F * CIN);
            int f = rem >> 8, c = rem & 255;
            Wt1[i] = f2bf(W1[(f * CIN + c) * 3 + kk]);
        }
        if (i < 3 * F * F) {
            int kk = i / (F * F);
            int rem = i - kk * (F * F);
            int f = rem >> 7, c = rem & 127;
            Wt2[i] = f2bf(W2[(f * F + c) * 3 + kk]);
        }
    }
    if (blockIdx.x >= 8) return;
    __shared__ float is[Z];
    __shared__ float sh1[CIN];
    __shared__ float sh2[F];
    int b = blockIdx.x;
    if (t < Z) is[t] = istyle[b * Z + t];
    __syncthreads();
    {
        float acc = 0.f;
        const float* w = s1w + (size_t)t * Z;
        for (int z = 0; z < Z; z += 4) {
            float4 v = *(const float4*)(w + z);
            acc += v.x * is[z] + v.y * is[z + 1] + v.z * is[z + 2] + v.w * is[z + 3];
        }
        float v = acc + s1b[t] + 1.0f;
        sh1[t] = v;
        s1[b * CIN + t] = v;
    }
    if (t < F) {
        float a2 = 0.f, a3 = 0.f;
        const float* w2 = s2w + (size_t)t * Z;
        const float* w3 = rgbw + (size_t)t * Z;
        for (int z = 0; z < Z; z += 4) {
            float4 u2 = *(const float4*)(w2 + z);
            float4 u3 = *(const float4*)(w3 + z);
            a2 += u2.x * is[z] + u2.y * is[z + 1] + u2.z * is[z + 2] + u2.w * is[z + 3];
            a3 += u3.x * is[z] + u3.y * is[z + 1] + u3.z * is[z + 2] + u3.w * is[z + 3];
        }
        float v2 = a2 + s2b[t] + 1.0f;
        sh2[t] = v2;
        s2[b * F + t] = v2;
        srgbS[b * F + t] = (a3 + rgbb[t] + 1.0f) * rgbcw[t];
    }
    __syncthreads();
    if (t < F) {
        float acc = 0.f;
        const float* w = W1 + (size_t)t * CIN * 3;
        for (int c = 0; c < CIN; c += 4) {
            float4 va = *(const float4*)(w + c * 3);
            float4 vb = *(const float4*)(w + c * 3 + 4);
            float4 vc = *(const float4*)(w + c * 3 + 8);
            float s0 = sh1[c], s1v = sh1[c + 1], s2v = sh1[c + 2], s3 = sh1[c + 3];
            acc += s0 * s0 * (va.x * va.x + va.y * va.y + va.z * va.z);
            acc += s1v * s1v * (va.w * va.w + vb.x * vb.x + vb.y * vb.y);
            acc += s2v * s2v * (vb.z * vb.z + vb.w * vb.w + vc.x * vc.x);
            acc += s3 * s3 * (vc.y * vc.y + vc.z * vc.z + vc.w * vc.w);
        }
        d1[b * F + t] = rsqrtf(acc + EPS);
    } else {
        int f = t - F;
        float acc = 0.f;
        const float* w = W2 + (size_t)f * F * 3;
        for (int c = 0; c < F; c += 4) {
            float4 va = *(const float4*)(w + c * 3);
            float4 vb = *(const float4*)(w + c * 3 + 4);
            float4 vc = *(const float4*)(w + c * 3 + 8);
            float s0 = sh2[c], s1v = sh2[c + 1], s2v = sh2[c + 2], s3 = sh2[c + 3];
            acc += s0 * s0 * (va.x * va.x + va.y * va.y + va.z * va.z);
            acc += s1v * s1v * (va.w * va.w + vb.x * vb.x + vb.y * vb.y);
            acc += s2v * s2v * (vb.z * vb.z + vb.w * vb.w + vc.x * vc.x);
            acc += s3 * s3 * (vc.y * vc.y + vc.z * vc.z + vc.w * vc.w);
        }
        d2[b * F + f] = rsqrtf(acc + EPS);
    }
}

// ---------------- prep: xt[b][l][c] = upsample(x)*s1, bf16 (parked in d_out) ----------
__global__ __launch_bounds__(256) void k_prepx(const float* __restrict__ x,
                                               const float* __restrict__ s1,
                                               unsigned short* __restrict__ xt) {
    int b = blockIdx.z, c0 = blockIdx.y * 64, l0 = blockIdx.x * 64;
    int t = threadIdx.x;
    __shared__ float xj[64][37];
    int j0 = (l0 >> 1) - 1;
    for (int idx = t; idx < 64 * 34; idx += 256) {
        int c = idx / 34, jj = idx - c * 34;
        int j = j0 + jj;
        j = j < 0 ? 0 : (j > L - 1 ? L - 1 : j);
        xj[c][jj] = x[((size_t)(b * CIN + c0 + c)) * L + j];
    }
    __syncthreads();
    int c = t & 63;
    int lg = t >> 6;
    float s = s1[b * CIN + c0 + c];
    for (int li = 0; li < 16; ++li) {
        int ll = lg * 16 + li;
        int l = l0 + ll;
        int j = l >> 1;
        int jj = j - j0;
        float v;
        if (l & 1) {
            v = 0.75f * xj[c][jj] + 0.25f * xj[c][jj + 1];
        } else {
            v = (j == 0) ? xj[c][jj] : (0.25f * xj[c][jj - 1] + 0.75f * xj[c][jj]);
        }
        xt[((size_t)(b * LU + l)) * CIN + c0 + c] = f2bf(v * s);
    }
}

#define WSTEP(N0, N1)                                                       \
    if (w0) { asm volatile("s_waitcnt vmcnt(" #N0 ")" ::: "memory"); }      \
    else    { asm volatile("s_waitcnt vmcnt(" #N1 ")" ::: "memory"); }      \
    __builtin_amdgcn_s_barrier();                                           \
    __builtin_amdgcn_sched_barrier(0);

// ---------------- MEGA: conv1 (512 blocks) || n1pre (1024) || n2pre (1024) ------------
// conv1 body verbatim (r5-r19 proven). n1pre/n2pre = r19 MFMA noise-GEMM bodies with
// plain bf16 stores to n1buf/n2buf (no RMW). Co-resident blocks overlap the 420 MB
// noise-weight stream with conv1's MFMA compute.
__global__ __launch_bounds__(256) void k_mega(const unsigned short* __restrict__ xt,
                                              const unsigned short* __restrict__ Wt1,
                                              const float* __restrict__ d1,
                                              unsigned short* __restrict__ y1,
                                              const float* __restrict__ nw1,
                                              const float* __restrict__ nw2,
                                              const float* __restrict__ inoise,
                                              unsigned short* __restrict__ n1buf,
                                              unsigned short* __restrict__ n2buf) {
    __shared__ float lds[2][6400];
    const int bid = blockIdx.x;
    const int t = threadIdx.x;
    const int lane = t & 63, wv = t >> 6;

    if (bid < 512) {
        // ---- conv1 ----
        const int b0 = ((bid >> 6) & 3) * 2;
        const int l0 = (bid & 63) * 64;
        const int nfb = (bid >> 8) * 4;
        const int lbase = l0 + wv * 16;
        const int m = lane & 15, ks = lane >> 4;

        f32x4 acc[2][4];
#pragma unroll
        for (int bb = 0; bb < 2; ++bb)
#pragma unroll
            for (int nf = 0; nf < 4; ++nf) acc[bb][nf] = (f32x4)0.f;

        const unsigned short* xb0 = xt + ((size_t)(b0 + 0) * LU) * CIN + ks * 8;
        const unsigned short* xb1 = xt + ((size_t)(b0 + 1) * LU) * CIN + ks * 8;

#pragma unroll 2
        for (int kc = 0; kc < 8; ++kc) {
#pragma unroll
            for (int kk = 0; kk < 3; ++kk) {
                int lA = lbase + m + kk - 1;
                bf16x8 a0 = (bf16x8)0, a1 = (bf16x8)0;
                if (lA >= 0 && lA < LU) {
                    a0 = *(const bf16x8*)&xb0[(size_t)lA * CIN + kc * 32];
                    a1 = *(const bf16x8*)&xb1[(size_t)lA * CIN + kc * 32];
                }
#pragma unroll
                for (int nf = 0; nf < 4; ++nf) {
                    const bf16x8 w =
                        *(const bf16x8*)&Wt1[((kk * F + (nfb + nf) * 16 + m) << 8) + kc * 32 + ks * 8];
                    acc[0][nf] = __builtin_amdgcn_mfma_f32_16x16x32_bf16(a0, w, acc[0][nf], 0, 0, 0);
                    acc[1][nf] = __builtin_amdgcn_mfma_f32_16x16x32_bf16(a1, w, acc[1][nf], 0, 0, 0);
                }
            }
        }
#pragma unroll
        for (int bb = 0; bb < 2; ++bb) {
            int b = b0 + bb;
#pragma unroll
            for (int nf = 0; nf < 4; ++nf) {
                int f = (nfb + nf) * 16 + m;
                float dm = d1[b * F + f];
#pragma unroll
                for (int q = 0; q < 4; ++q) {
                    int l = lbase + ks * 4 + q;
                    y1[((size_t)(b * LU + l) << 7) + f] = f2bf(acc[bb][nf][q] * dm);
                }
            }
        }
        return;
    }

    // ---- shared noise-GEMM pieces ----
    const int n = lane & 15, ks = lane >> 4;
    const bool w0 = (t >> 6) == 0;
    const int r = wv * 16 + n;

    bf16x8 af[4];
#pragma unroll
    for (int ck = 0; ck < 4; ++ck) {
        bf16x8 a = (bf16x8)0;
        if (n < 8) {
            const float* ap = inoise + n * NZ;
#pragma unroll
            for (int j = 0; j < 8; ++j) {
                int z = ck * 32 + ks * 8 + j;
                if (z < NZ) a[j] = (short)f2bf(ap[z]);
            }
        }
        af[ck] = a;
    }

    if (bid < 1536) {
        // ---- n1pre: n1buf[b][l*F+f] = inoise@nw1.T (rows f*LU+l) ----
        const int bid2 = bid - 512;
        const int f0 = (bid2 >> 8) * 32;
        const int l0 = (bid2 & 255) * 16;
        const int fseg = r >> 1, dl = r & 1;
        const int f = f0 + fseg;

        auto stage = [&](int buf, int cc) {
            const int lbase = l0 + 2 * cc;
#pragma unroll
            for (int rr = 0; rr < 7; ++rr) {
                int g = rr * 256 + t;
                if (g < 1600) {
                    int fs = g / 50;
                    int rem = g - fs * 50;
                    int d2v = (rem >= 25) ? 1 : 0;
                    int m = rem - 25 * d2v;
                    const float* src = nw1 + ((size_t)(f0 + fs) * LU + lbase + d2v) * NZ + m * 4;
                    gload_lds16(src, &lds[buf][g * 4]);
                }
            }
        };
        auto compute = [&](int buf, int cc) {
            const float* rowp = &lds[buf][r * 100];
            f32x4 acc = (f32x4)0.f;
#pragma unroll
            for (int ck = 0; ck < 3; ++ck) {
                float4 u0 = *(const float4*)&rowp[ck * 32 + ks * 8];
                float4 u1 = *(const float4*)&rowp[ck * 32 + ks * 8 + 4];
                acc = __builtin_amdgcn_mfma_f32_16x16x32_bf16(af[ck], cvtfrag(u0, u1), acc, 0, 0, 0);
            }
            {
                bf16x8 b3 = (bf16x8)0;
                if (ks == 0) {
                    float4 u = *(const float4*)&rowp[96];
                    unsigned p0 = pack2(u.x, u.y), p1 = pack2(u.z, u.w);
                    b3[0] = (short)(p0 & 0xffff); b3[1] = (short)(p0 >> 16);
                    b3[2] = (short)(p1 & 0xffff); b3[3] = (short)(p1 >> 16);
                }
                acc = __builtin_amdgcn_mfma_f32_16x16x32_bf16(af[3], b3, acc, 0, 0, 0);
            }
            if (ks < 2) {
                const int l = l0 + 2 * cc + dl;
                const size_t i = (size_t)l * F + f;
#pragma unroll
                for (int q = 0; q < 4; ++q)
                    n1buf[(size_t)(ks * 4 + q) * S + i] = f2bf(acc[q]);
            }
        };

        stage(0, 0);
        stage(1, 1);
        WSTEP(7, 6)              compute(0, 0);
        WSTEP(4, 4) stage(0, 2); compute(1, 1);
        WSTEP(4, 4) stage(1, 3); compute(0, 2);
        WSTEP(4, 4) stage(0, 4); compute(1, 3);
        WSTEP(4, 4) stage(1, 5); compute(0, 4);
        WSTEP(4, 4) stage(0, 6); compute(1, 5);
        WSTEP(4, 4) stage(1, 7); compute(0, 6);
        WSTEP(4, 4)              compute(1, 7);
        return;
    }

    // ---- n2pre: n2buf[b][i] = inoise@nw2.T (rows i contiguous) ----
    const int bid3 = bid - 1536;
    const int row0 = bid3 * 512;

    auto stage2 = [&](int buf, int cc) {
        const float* src0 = nw2 + ((size_t)row0 + cc * 64) * NZ;
#pragma unroll
        for (int rr = 0; rr < 7; ++rr) {
            int g = rr * 256 + t;
            if (g < 1600) gload_lds16(src0 + g * 4, &lds[buf][g * 4]);
        }
    };
    auto compute2 = [&](int buf, int cc) {
        const float* rowp = &lds[buf][r * 100];
        f32x4 acc = (f32x4)0.f;
#pragma unroll
        for (int ck = 0; ck < 3; ++ck) {
            float4 u0 = *(const float4*)&rowp[ck * 32 + ks * 8];
            float4 u1 = *(const float4*)&rowp[ck * 32 + ks * 8 + 4];
            acc = __builtin_amdgcn_mfma_f32_16x16x32_bf16(af[ck], cvtfrag(u0, u1), acc, 0, 0, 0);
        }
        {
            bf16x8 b3 = (bf16x8)0;
            if (ks == 0) {
                float4 u = *(const float4*)&rowp[96];
                unsigned p0 = pack2(u.x, u.y), p1 = pack2(u.z, u.w);
                b3[0] = (short)(p0 & 0xffff); b3[1] = (short)(p0 >> 16);
                b3[2] = (short)(p1 & 0xffff); b3[3] = (short)(p1 >> 16);
            }
            acc = __builtin_amdgcn_mfma_f32_16x16x32_bf16(af[3], b3, acc, 0, 0, 0);
        }
        if (ks < 2) {
            const size_t i = (size_t)row0 + cc * 64 + r;
#pragma unroll
            for (int q = 0; q < 4; ++q)
                n2buf[(size_t)(ks * 4 + q) * S + i] = f2bf(acc[q]);
        }
    };

    stage2(0, 0);
    stage2(1, 1);
    WSTEP(7, 6)               compute2(0, 0);
    WSTEP(4, 4) stage2(0, 2); compute2(1, 1);
    WSTEP(4, 4) stage2(1, 3); compute2(0, 2);
    WSTEP(4, 4) stage2(0, 4); compute2(1, 3);
    WSTEP(4, 4) stage2(1, 5); compute2(0, 4);
    WSTEP(4, 4) stage2(0, 6); compute2(1, 5);
    WSTEP(4, 4) stage2(1, 7); compute2(0, 6);
    WSTEP(4, 4)               compute2(1, 7);
}
#undef WSTEP

// ---------------- apply1: y1 = lrelu(y1 + n1) * s2 (in place, coalesced) --------------
__global__ __launch_bounds__(256) void k_apply1(unsigned short* y1,
                                                const unsigned short* __restrict__ n1,
                                                const float* __restrict__ s2) {
    __shared__ float s2s[B][F];
    int t = threadIdx.x;
    for (int idx = t; idx < B * F; idx += 256) s2s[idx >> 7][idx & 127] = s2[idx];
    __syncthreads();
    int i = blockIdx.x * 256 + t;
    int f = i & 127;
#pragma unroll
    for (int bb = 0; bb < B; ++bb) {
        size_t a = (size_t)bb * S + i;
        float v = bf2f(y1[a]) + bf2f(n1[a]);
        v = v >= 0.f ? v : LEAK * v;
        y1[a] = f2bf(v * s2s[bb][f]);
    }
}

// ---------------- conv2 MFMA + fused noise2 epilogue ----------------------------------
__global__ __launch_bounds__(256) void k_conv2(const unsigned short* __restrict__ y1n,
                                               const unsigned short* __restrict__ Wt2,
                                               const float* __restrict__ d2,
                                               const unsigned short* __restrict__ n2buf,
                                               float* __restrict__ xout) {
    const int b0 = blockIdx.y * 2;
    const int l0 = blockIdx.x * 64;
    const int mfb = blockIdx.z * 4;
    const int lane = threadIdx.x & 63, wv = threadIdx.x >> 6;
    const int lbase = l0 + wv * 16;
    const int m = lane & 15, ks = lane >> 4;

    f32x4 acc[2][4];
#pragma unroll
    for (int bb = 0; bb < 2; ++bb)
#pragma unroll
        for (int mf = 0; mf < 4; ++mf) acc[bb][mf] = (f32x4)0.f;

    const unsigned short* yb0 = y1n + ((size_t)(b0 + 0) * LU) * F + ks * 8;
    const unsigned short* yb1 = y1n + ((size_t)(b0 + 1) * LU) * F + ks * 8;

#pragma unroll 2
    for (int kc = 0; kc < 4; ++kc) {
#pragma unroll
        for (int kk = 0; kk < 3; ++kk) {
            int lB = lbase + m + kk - 1;
            bf16x8 bv0 = (bf16x8)0, bv1 = (bf16x8)0;
            if (lB >= 0 && lB < LU) {
                bv0 = *(const bf16x8*)&yb0[(size_t)lB * F + kc * 32];
                bv1 = *(const bf16x8*)&yb1[(size_t)lB * F + kc * 32];
            }
#pragma unroll
            for (int mf = 0; mf < 4; ++mf) {
                const bf16x8 w =
                    *(const bf16x8*)&Wt2[((kk * F + (mfb + mf) * 16 + m) << 7) + kc * 32 + ks * 8];
                acc[0][mf] = __builtin_amdgcn_mfma_f32_16x16x32_bf16(w, bv0, acc[0][mf], 0, 0, 0);
                acc[1][mf] = __builtin_amdgcn_mfma_f32_16x16x32_bf16(w, bv1, acc[1][mf], 0, 0, 0);
            }
        }
    }
#pragma unroll
    for (int bb = 0; bb < 2; ++bb) {
        int b = b0 + bb;
#pragma unroll
        for (int mf = 0; mf < 4; ++mf) {
#pragma unroll
            for (int q = 0; q < 4; ++q) {
                int f = (mfb + mf) * 16 + ks * 4 + q;
                int l = lbase + m;
                size_t i = ((size_t)f << 12) + l;
                float val = acc[bb][mf][q] * d2[b * F + f] + bf2f(n2buf[(size_t)b * S + i]);
                val = val >= 0.f ? val : LEAK * val;
                xout[(size_t)b * S + i] = val;
            }
        }
    }
}

// ---------------- rgb fused (unchanged) ----------------
__global__ __launch_bounds__(256) void k_rgb(const float* __restrict__ xf,
                                             const float* __restrict__ srgbS,
                                             const float* __restrict__ prev,
                                             float* __restrict__ rgb) {
    int b = blockIdx.y;
    int o0 = blockIdx.x * 512;
    int t = threadIdx.x;
    __shared__ float ss[F];
    __shared__ float pre[258];
    if (t < F) ss[t] = srgbS[b * F + t];
    __syncthreads();
    int j0 = (o0 >> 1) - 1;
    for (int jj = t; jj < 258; jj += 256) {
        int j = j0 + jj;
        j = j < 0 ? 0 : (j > LU - 1 ? LU - 1 : j);
        float acc = prev[b * LU + j];
        const float* xb = xf + (size_t)b * S + j;
        for (int f = 0; f < F; ++f) acc += xb[(size_t)f * LU] * ss[f];
        pre[jj] = acc;
    }
    __syncthreads();
    int jj = t + 1;
    int j = j0 + jj;
    float ve = (j == 0) ? pre[jj] : (0.25f * pre[jj - 1] + 0.75f * pre[jj]);
    float vo = 0.75f * pre[jj] + 0.25f * pre[jj + 1];
    float2 v2 = make_float2(ve, vo);
    *(float2*)&rgb[(size_t)b * 2 * LU + o0 + 2 * t] = v2;
}

extern "C" void kernel_launch(void* const* d_in, const int* in_sizes, int n_in,
                              void* d_out, int out_size, void* d_ws, size_t ws_size,
                              hipStream_t stream) {
    const float* x      = (const float*)d_in[0];
    const float* prev   = (const float*)d_in[1];
    const float* istyle = (const float*)d_in[2];
    const float* inoise = (const float*)d_in[3];
    const float* s1w    = (const float*)d_in[4];
    const float* s1b    = (const float*)d_in[5];
    const float* W1     = (const float*)d_in[6];
    const float* nw1    = (const float*)d_in[7];
    const float* s2w    = (const float*)d_in[8];
    const float* s2b    = (const float*)d_in[9];
    const float* W2     = (const float*)d_in[10];
    const float* nw2    = (const float*)d_in[11];
    const float* rgbw   = (const float*)d_in[12];
    const float* rgbb   = (const float*)d_in[13];
    const float* rgbcw  = (const float*)d_in[14];

    char* w = (char*)d_ws;
    float* s1      = (float*)(w);                             // 8 KB
    float* s2      = (float*)(w + 8 * 1024);                  // 4 KB
    float* srgbS   = (float*)(w + 12 * 1024);                 // 4 KB
    float* d1      = (float*)(w + 16 * 1024);                 // 4 KB
    float* d2      = (float*)(w + 20 * 1024);                 // 4 KB
    unsigned short* Wt1 = (unsigned short*)(w + 256 * 1024);  // 192 KB
    unsigned short* Wt2 = (unsigned short*)(w + 448 * 1024);  // 96 KB
    unsigned short* y1    = (unsigned short*)(w + (size_t)1 * 1024 * 1024);   // 8 MB
    unsigned short* n1buf = (unsigned short*)(w + (size_t)10 * 1024 * 1024);  // 8.4 MB
    unsigned short* n2buf = (unsigned short*)(w + (size_t)19 * 1024 * 1024);  // 8.4 MB

    unsigned short* xt = (unsigned short*)d_out;  // parked; dead once conv2 writes xout

    float* xout   = (float*)d_out;
    float* rgbout = xout + (size_t)B * S;

    k_styles<<<384, 256, 0, stream>>>(istyle, s1w, s1b, s2w, s2b, rgbw, rgbb, rgbcw,
                                      W1, W2, s1, s2, srgbS, d1, d2, Wt1, Wt2);
    k_prepx<<<dim3(LU / 64, CIN / 64, B), 256, 0, stream>>>(x, s1, xt);
    k_mega<<<2560, 256, 0, stream>>>(xt, Wt1, d1, y1, nw1, nw2, inoise, n1buf, n2buf);
    k_apply1<<<S / 256, 256, 0, stream>>>(y1, n1buf, s2);
    k_conv2<<<dim3(LU / 64, B / 2, 2), 256, 0, stream>>>(y1, Wt2, d2, n2buf, xout);
    k_rgb<<<dim3(2 * LU / 512, B), 256, 0, stream>>>(xout, srgbS, prev, rgbout);
}